// Round 1
// baseline (12412.573 us; speedup 1.0000x reference)
//
#include <hip/hip_runtime.h>
#include <math.h>

// Problem constants
#define B_   16
#define NC_  12
#define L_   500
#define D_   256
#define NG   (B_*NC_)    // 192 graphs
#define MROWS (NG*L_)    // 96000 rows

__device__ __forceinline__ float gelu_f(float x) {
    return 0.5f * x * (1.0f + erff(x * 0.70710678118654752f));
}

// ---------------------------------------------------------------------------
// Generic fp32 GEMM: C[M,N] = A[M,K] @ W[K,N] + bias[N]
// 64x64 block tile, BK=16, 256 threads, 4x4 per thread.
// ---------------------------------------------------------------------------
__global__ __launch_bounds__(256) void gemm_bias_f32(
    const float* __restrict__ A, const float* __restrict__ W,
    const float* __restrict__ bias, float* __restrict__ C,
    int M, int N, int K)
{
    __shared__ __align__(16) float As[64 * 17];
    __shared__ __align__(16) float Bs[16 * 68];
    int t  = threadIdx.x;
    int tx = t & 15, ty = t >> 4;
    int m0 = blockIdx.x * 64;
    int n0 = blockIdx.y * 64;
    float acc[4][4] = {};
    int ktiles = (K + 15) >> 4;
    for (int kt = 0; kt < ktiles; ++kt) {
        int k0 = kt << 4;
        {   // A tile 64x16
            int e = t * 4;
            int r = e >> 4, c = e & 15;
            int row = m0 + r;
            #pragma unroll
            for (int jj = 0; jj < 4; ++jj) {
                int k = k0 + c + jj;
                As[r * 17 + c + jj] = (row < M && k < K) ? A[(long)row * K + k] : 0.0f;
            }
        }
        {   // B tile 16x64
            int e = t * 4;
            int r = e >> 6, c = e & 63;
            int k = k0 + r;
            #pragma unroll
            for (int jj = 0; jj < 4; ++jj) {
                int col = n0 + c + jj;
                Bs[r * 68 + c + jj] = (k < K && col < N) ? W[(long)k * N + col] : 0.0f;
            }
        }
        __syncthreads();
        #pragma unroll
        for (int kk = 0; kk < 16; ++kk) {
            float a0 = As[(ty * 4 + 0) * 17 + kk];
            float a1 = As[(ty * 4 + 1) * 17 + kk];
            float a2 = As[(ty * 4 + 2) * 17 + kk];
            float a3 = As[(ty * 4 + 3) * 17 + kk];
            float4 b = *(const float4*)&Bs[kk * 68 + tx * 4];
            acc[0][0] += a0 * b.x; acc[0][1] += a0 * b.y; acc[0][2] += a0 * b.z; acc[0][3] += a0 * b.w;
            acc[1][0] += a1 * b.x; acc[1][1] += a1 * b.y; acc[1][2] += a1 * b.z; acc[1][3] += a1 * b.w;
            acc[2][0] += a2 * b.x; acc[2][1] += a2 * b.y; acc[2][2] += a2 * b.z; acc[2][3] += a2 * b.w;
            acc[3][0] += a3 * b.x; acc[3][1] += a3 * b.y; acc[3][2] += a3 * b.z; acc[3][3] += a3 * b.w;
        }
        __syncthreads();
    }
    #pragma unroll
    for (int u = 0; u < 4; ++u) {
        int row = m0 + ty * 4 + u;
        if (row >= M) continue;
        #pragma unroll
        for (int v = 0; v < 4; ++v) {
            int col = n0 + tx * 4 + v;
            if (col >= N) continue;
            float bv = bias ? bias[col] : 0.0f;
            C[(long)row * N + col] = acc[u][v] + bv;
        }
    }
}

// ---------------------------------------------------------------------------
// Row sum-of-squares for Y (rows x 256)
// ---------------------------------------------------------------------------
__global__ __launch_bounds__(256) void rowsumsq(
    const float* __restrict__ Y, float* __restrict__ n2, int rows)
{
    int t = threadIdx.x;
    int w = t >> 6, lane = t & 63;
    long row = (long)blockIdx.x * 4 + w;
    if (row >= rows) return;
    float4 v = *(const float4*)&Y[row * 256 + lane * 4];
    float s = v.x * v.x + v.y * v.y + v.z * v.z + v.w * v.w;
    s += __shfl_xor(s, 1, 64);  s += __shfl_xor(s, 2, 64);
    s += __shfl_xor(s, 4, 64);  s += __shfl_xor(s, 8, 64);
    s += __shfl_xor(s, 16, 64); s += __shfl_xor(s, 32, 64);
    if (lane == 0) n2[row] = s;
}

// ---------------------------------------------------------------------------
// Fused graph layer: flash-style distance-softmax + P@Y + LN + GELU + residual
// grid (32 row-tiles, 192 graphs), 256 threads.
// Thread (i=t/16, j=t%16): lane group of 16 consecutive lanes = one Q row.
// Each thread owns output dims [j*16, j*16+16) of row i.
// ---------------------------------------------------------------------------
__global__ __launch_bounds__(256) void graph_attn_f32(
    const float* __restrict__ Y, const float* __restrict__ n2,
    const float* __restrict__ Xin, float* __restrict__ Xout,
    const float* __restrict__ gamma, const float* __restrict__ beta,
    const float* __restrict__ alpha_p, const float* __restrict__ lamda_p,
    int cross)
{
    __shared__ __align__(16) float qs[16 * 256];
    __shared__ __align__(16) float ys[16 * 260];
    __shared__ float x2s[16];
    __shared__ float q2s[16];
    int t  = threadIdx.x;
    int n  = blockIdx.y;            // graph
    int rt = blockIdx.x;            // row tile
    int qn = cross ? (n / NC_) * NC_ : n;
    int i = t >> 4;
    int j = t & 15;
    float lam = lamda_p[0];

    // Stage Q tile (16 rows of graph qn)
    #pragma unroll
    for (int rep = 0; rep < 4; ++rep) {
        int fi = t + rep * 256;      // float4 index, 64 per row
        int r = fi >> 6;
        int c = (fi & 63) << 2;
        int gi = rt * 16 + r;
        float4 v = make_float4(0.f, 0.f, 0.f, 0.f);
        if (gi < L_) v = *(const float4*)&Y[((long)qn * L_ + gi) * D_ + c];
        *(float4*)&qs[r * 256 + c] = v;
    }
    if (t < 16) {
        int gi = rt * 16 + t;
        q2s[t] = (gi < L_) ? n2[qn * L_ + gi] : 0.0f;
    }
    __syncthreads();

    float q2 = q2s[i];
    int gi = rt * 16 + i;
    float m = -3.0e38f;
    float ssum = 0.0f;
    float acc[16];
    #pragma unroll
    for (int u = 0; u < 16; ++u) acc[u] = 0.0f;

    for (int jt = 0; jt < 32; ++jt) {
        int j0 = jt * 16;
        __syncthreads();   // protect ys from previous iteration
        #pragma unroll
        for (int rep = 0; rep < 4; ++rep) {
            int fi = t + rep * 256;
            int r = fi >> 6;
            int c = (fi & 63) << 2;
            int gj = j0 + r;
            float4 v = make_float4(0.f, 0.f, 0.f, 0.f);
            if (gj < L_) v = *(const float4*)&Y[((long)n * L_ + gj) * D_ + c];
            *(float4*)&ys[r * 260 + c] = v;
        }
        if (t < 16) {
            int gj = j0 + t;
            x2s[t] = (gj < L_) ? n2[n * L_ + gj] : 0.0f;
        }
        __syncthreads();

        // S = q_i . y_j
        float s0 = 0.f, s1 = 0.f, s2 = 0.f, s3 = 0.f;
        const float* qrow = &qs[i * 256];
        const float* yrow = &ys[j * 260];
        #pragma unroll 8
        for (int k4 = 0; k4 < 64; ++k4) {
            float4 a = *(const float4*)&qrow[k4 * 4];
            float4 b = *(const float4*)&yrow[k4 * 4];
            s0 += a.x * b.x; s1 += a.y * b.y; s2 += a.z * b.z; s3 += a.w * b.w;
        }
        float S = (s0 + s1) + (s2 + s3);
        int gj = j0 + j;
        float logit;
        if (gj < L_) {
            float d2 = fmaxf(q2 + x2s[j] - 2.0f * S, 0.0f);
            logit = -2.0f * sqrtf(d2) + ((gi == gj) ? lam : 0.0f);
        } else {
            logit = -1.0e30f;
        }
        // online softmax across the 16-lane row group
        float tm = logit;
        tm = fmaxf(tm, __shfl_xor(tm, 1, 16));
        tm = fmaxf(tm, __shfl_xor(tm, 2, 16));
        tm = fmaxf(tm, __shfl_xor(tm, 4, 16));
        tm = fmaxf(tm, __shfl_xor(tm, 8, 16));
        float mnew   = fmaxf(m, tm);
        float factor = expf(m - mnew);
        float p      = expf(logit - mnew);
        ssum = ssum * factor + p;
        #pragma unroll
        for (int u = 0; u < 16; ++u) acc[u] *= factor;
        m = mnew;
        // acc += p_jj * y_jj[j*16 .. +16)
        #pragma unroll
        for (int jj = 0; jj < 16; ++jj) {
            float pj = __shfl(p, jj, 16);
            const float* yr = &ys[jj * 260 + j * 16];
            #pragma unroll
            for (int u4 = 0; u4 < 4; ++u4) {
                float4 b = *(const float4*)&yr[u4 * 4];
                acc[u4 * 4 + 0] += pj * b.x;
                acc[u4 * 4 + 1] += pj * b.y;
                acc[u4 * 4 + 2] += pj * b.z;
                acc[u4 * 4 + 3] += pj * b.w;
            }
        }
    }

    // normalize
    float l = ssum;
    l += __shfl_xor(l, 1, 16); l += __shfl_xor(l, 2, 16);
    l += __shfl_xor(l, 4, 16); l += __shfl_xor(l, 8, 16);
    float inv = 1.0f / l;
    float lsum = 0.0f;
    #pragma unroll
    for (int u = 0; u < 16; ++u) { acc[u] *= inv; lsum += acc[u]; }
    // LN over 256 dims (16 local x 16 lanes)
    float msum = lsum;
    msum += __shfl_xor(msum, 1, 16); msum += __shfl_xor(msum, 2, 16);
    msum += __shfl_xor(msum, 4, 16); msum += __shfl_xor(msum, 8, 16);
    float mean = msum * (1.0f / 256.0f);
    float vs = 0.0f;
    #pragma unroll
    for (int u = 0; u < 16; ++u) { float d = acc[u] - mean; vs += d * d; }
    vs += __shfl_xor(vs, 1, 16); vs += __shfl_xor(vs, 2, 16);
    vs += __shfl_xor(vs, 4, 16); vs += __shfl_xor(vs, 8, 16);
    float rs = rsqrtf(vs * (1.0f / 256.0f) + 1e-6f);
    float a = fminf(fmaxf(alpha_p[0], 0.1f), 0.9f);

    if (gi < L_) {
        long base = ((long)n * L_ + gi) * D_ + j * 16;
        #pragma unroll
        for (int u4 = 0; u4 < 4; ++u4) {
            float4 xin = *(const float4*)&Xin[base + u4 * 4];
            float4 o;
            float hn, gl;
            hn = gamma[j*16 + u4*4 + 0] * (acc[u4*4+0] - mean) * rs + beta[j*16 + u4*4 + 0];
            gl = gelu_f(hn); o.x = (1.0f - a) * xin.x + a * gl;
            hn = gamma[j*16 + u4*4 + 1] * (acc[u4*4+1] - mean) * rs + beta[j*16 + u4*4 + 1];
            gl = gelu_f(hn); o.y = (1.0f - a) * xin.y + a * gl;
            hn = gamma[j*16 + u4*4 + 2] * (acc[u4*4+2] - mean) * rs + beta[j*16 + u4*4 + 2];
            gl = gelu_f(hn); o.z = (1.0f - a) * xin.z + a * gl;
            hn = gamma[j*16 + u4*4 + 3] * (acc[u4*4+3] - mean) * rs + beta[j*16 + u4*4 + 3];
            gl = gelu_f(hn); o.w = (1.0f - a) * xin.w + a * gl;
            *(float4*)&Xout[base + u4 * 4] = o;
        }
    }
}

// ---------------------------------------------------------------------------
// Fused dimension-reduction MLP: 256->64->32->16->1, LN+GELU between.
// One wave per row; 4 rows per 256-thread block.
// ---------------------------------------------------------------------------
__global__ __launch_bounds__(256) void dr_mlp(
    const float* __restrict__ X, float* __restrict__ xs,
    const float* __restrict__ W1, const float* __restrict__ b1,
    const float* __restrict__ g1, const float* __restrict__ be1,
    const float* __restrict__ W2, const float* __restrict__ b2,
    const float* __restrict__ g2, const float* __restrict__ be2,
    const float* __restrict__ W3, const float* __restrict__ b3,
    const float* __restrict__ g3, const float* __restrict__ be3,
    const float* __restrict__ W4, const float* __restrict__ b4)
{
    __shared__ __align__(16) float xrow[4][256];
    __shared__ float s1[4][64];
    __shared__ float s2[4][32];
    __shared__ float s3[4][16];
    int t = threadIdx.x;
    int w = t >> 6, lane = t & 63;
    long row = (long)blockIdx.x * 4 + w;

    *(float4*)&xrow[w][lane * 4] = *(const float4*)&X[row * 256 + lane * 4];

    // dr1: 256 -> 64
    int o = lane;
    float a0 = 0.f, a1 = 0.f, a2 = 0.f, a3 = 0.f;
    #pragma unroll 8
    for (int k4 = 0; k4 < 64; ++k4) {
        float4 xv = *(const float4*)&xrow[w][k4 * 4];
        a0 += xv.x * W1[(k4 * 4 + 0) * 64 + o];
        a1 += xv.y * W1[(k4 * 4 + 1) * 64 + o];
        a2 += xv.z * W1[(k4 * 4 + 2) * 64 + o];
        a3 += xv.w * W1[(k4 * 4 + 3) * 64 + o];
    }
    float acc = b1[o] + ((a0 + a1) + (a2 + a3));
    float sum = acc;
    #pragma unroll
    for (int off = 1; off < 64; off <<= 1) sum += __shfl_xor(sum, off, 64);
    float mean = sum * (1.0f / 64.0f);
    float dlt = acc - mean;
    float v2 = dlt * dlt;
    #pragma unroll
    for (int off = 1; off < 64; off <<= 1) v2 += __shfl_xor(v2, off, 64);
    float rs = rsqrtf(v2 * (1.0f / 64.0f) + 1e-6f);
    s1[w][o] = gelu_f(g1[o] * dlt * rs + be1[o]);

    // dr2: 64 -> 32 (lanes 32..63 duplicate lanes 0..31; benign)
    int o2 = lane & 31;
    float acc2 = b2[o2];
    #pragma unroll
    for (int k = 0; k < 64; ++k) acc2 += s1[w][k] * W2[k * 32 + o2];
    float sum2 = acc2;
    #pragma unroll
    for (int off = 1; off < 32; off <<= 1) sum2 += __shfl_xor(sum2, off, 32);
    float mean2 = sum2 * (1.0f / 32.0f);
    float d2 = acc2 - mean2;
    float v22 = d2 * d2;
    #pragma unroll
    for (int off = 1; off < 32; off <<= 1) v22 += __shfl_xor(v22, off, 32);
    float rs2 = rsqrtf(v22 * (1.0f / 32.0f) + 1e-6f);
    s2[w][o2] = gelu_f(g2[o2] * d2 * rs2 + be2[o2]);

    // dr3: 32 -> 16
    int o3 = lane & 15;
    float acc3 = b3[o3];
    #pragma unroll
    for (int k = 0; k < 32; ++k) acc3 += s2[w][k] * W3[k * 16 + o3];
    float sum3 = acc3;
    #pragma unroll
    for (int off = 1; off < 16; off <<= 1) sum3 += __shfl_xor(sum3, off, 16);
    float mean3 = sum3 * (1.0f / 16.0f);
    float d3 = acc3 - mean3;
    float v23 = d3 * d3;
    #pragma unroll
    for (int off = 1; off < 16; off <<= 1) v23 += __shfl_xor(v23, off, 16);
    float rs3 = rsqrtf(v23 * (1.0f / 16.0f) + 1e-6f);
    s3[w][o3] = gelu_f(g3[o3] * d3 * rs3 + be3[o3]);

    // dr4: 16 -> 1, GELU, squeeze
    float acc4 = b4[0];
    #pragma unroll
    for (int k = 0; k < 16; ++k) acc4 += s3[w][k] * W4[k];
    if (lane == 0) xs[row] = gelu_f(acc4);
}

// ---------------------------------------------------------------------------
// Img graph layer over NC=12 nodes, feature dim L=500. One block per (b, i).
// ---------------------------------------------------------------------------
__global__ __launch_bounds__(256) void img_layer(
    const float* __restrict__ Y2, float* __restrict__ xs,
    const float* __restrict__ gamma, const float* __restrict__ beta,
    const float* __restrict__ alpha_p, const float* __restrict__ lamda_p)
{
    __shared__ float ys[12][500];
    __shared__ float hs[500];
    __shared__ float wred[4][24];
    __shared__ float ps[12];
    __shared__ float stats[2];
    int t = threadIdx.x;
    int w = t >> 6, lane = t & 63;
    int b = blockIdx.x / 12;
    int i = blockIdx.x - b * 12;

    for (int idx = t; idx < 6000; idx += 256)
        ys[idx / 500][idx % 500] = Y2[(long)b * 6000 + idx];
    __syncthreads();

    float dloc[12], nloc[12];
    #pragma unroll
    for (int j = 0; j < 12; ++j) { dloc[j] = 0.f; nloc[j] = 0.f; }
    for (int k = t; k < 500; k += 256) {
        float yi = ys[i][k];
        #pragma unroll
        for (int j = 0; j < 12; ++j) {
            float yj = ys[j][k];
            dloc[j] += yi * yj;
            nloc[j] += yj * yj;
        }
    }
    #pragma unroll
    for (int q = 0; q < 24; ++q) {
        float v = (q < 12) ? dloc[q] : nloc[q - 12];
        v += __shfl_xor(v, 1, 64);  v += __shfl_xor(v, 2, 64);
        v += __shfl_xor(v, 4, 64);  v += __shfl_xor(v, 8, 64);
        v += __shfl_xor(v, 16, 64); v += __shfl_xor(v, 32, 64);
        if (lane == 0) wred[w][q] = v;
    }
    __syncthreads();
    if (t == 0) {
        float lam = lamda_p[0];
        float dot[12], nn[12];
        #pragma unroll
        for (int q = 0; q < 12; ++q) {
            dot[q] = wred[0][q] + wred[1][q] + wred[2][q] + wred[3][q];
            nn[q]  = wred[0][12+q] + wred[1][12+q] + wred[2][12+q] + wred[3][12+q];
        }
        float ni = nn[i];
        float lg[12];
        float mx = -3.0e38f;
        #pragma unroll
        for (int j = 0; j < 12; ++j) {
            float dd2 = fmaxf(ni + nn[j] - 2.0f * dot[j], 0.0f);
            lg[j] = -2.0f * sqrtf(dd2) + ((j == i) ? lam : 0.0f);
            mx = fmaxf(mx, lg[j]);
        }
        float se = 0.f;
        #pragma unroll
        for (int j = 0; j < 12; ++j) { lg[j] = expf(lg[j] - mx); se += lg[j]; }
        float inv = 1.0f / se;
        #pragma unroll
        for (int j = 0; j < 12; ++j) ps[j] = lg[j] * inv;
    }
    __syncthreads();
    float pl[12];
    #pragma unroll
    for (int j = 0; j < 12; ++j) pl[j] = ps[j];
    float lsum = 0.f;
    for (int k = t; k < 500; k += 256) {
        float h = 0.f;
        #pragma unroll
        for (int j = 0; j < 12; ++j) h += pl[j] * ys[j][k];
        hs[k] = h;
        lsum += h;
    }
    {
        float v = lsum;
        v += __shfl_xor(v, 1, 64);  v += __shfl_xor(v, 2, 64);
        v += __shfl_xor(v, 4, 64);  v += __shfl_xor(v, 8, 64);
        v += __shfl_xor(v, 16, 64); v += __shfl_xor(v, 32, 64);
        if (lane == 0) wred[w][0] = v;
    }
    __syncthreads();
    if (t == 0) stats[0] = (wred[0][0] + wred[1][0] + wred[2][0] + wred[3][0]) * (1.0f / 500.0f);
    __syncthreads();
    float mean = stats[0];
    float vloc = 0.f;
    for (int k = t; k < 500; k += 256) { float d = hs[k] - mean; vloc += d * d; }
    {
        float v = vloc;
        v += __shfl_xor(v, 1, 64);  v += __shfl_xor(v, 2, 64);
        v += __shfl_xor(v, 4, 64);  v += __shfl_xor(v, 8, 64);
        v += __shfl_xor(v, 16, 64); v += __shfl_xor(v, 32, 64);
        if (lane == 0) wred[w][1] = v;
    }
    __syncthreads();
    if (t == 0) stats[1] = rsqrtf((wred[0][1] + wred[1][1] + wred[2][1] + wred[3][1]) * (1.0f / 500.0f) + 1e-6f);
    __syncthreads();
    float rsv = stats[1];
    float a = fminf(fmaxf(alpha_p[0], 0.1f), 0.9f);
    for (int k = t; k < 500; k += 256) {
        float hn = gamma[k] * (hs[k] - mean) * rsv + beta[k];
        float gl = gelu_f(hn);
        long idx = ((long)b * 12 + i) * 500 + k;
        xs[idx] = (1.0f - a) * xs[idx] + a * gl;
    }
}

// ---------------------------------------------------------------------------
// Final scoring: global cosine, cls head, softmax combine. One block per b.
// ---------------------------------------------------------------------------
__global__ __launch_bounds__(256) void final_k(
    const float* __restrict__ qg, const float* __restrict__ cg,
    const float* __restrict__ xs, const float* __restrict__ clsW,
    const float* __restrict__ clsb, const float* __restrict__ ratio,
    float* __restrict__ out)
{
    __shared__ float gsb[11];
    int b = blockIdx.x;
    int t = threadIdx.x;
    int w = t >> 6, lane = t & 63;

    for (int j = w; j < 11; j += 4) {
        const float* q = &qg[b * 256];
        const float* c = &cg[((long)b * 11 + j) * 256];
        float4 qv = *(const float4*)&q[lane * 4];
        float4 cv = *(const float4*)&c[lane * 4];
        float dq  = qv.x * cv.x + qv.y * cv.y + qv.z * cv.z + qv.w * cv.w;
        float nq  = qv.x * qv.x + qv.y * qv.y + qv.z * qv.z + qv.w * qv.w;
        float ncv = cv.x * cv.x + cv.y * cv.y + cv.z * cv.z + cv.w * cv.w;
        #pragma unroll
        for (int off = 1; off < 64; off <<= 1) {
            dq  += __shfl_xor(dq, off, 64);
            nq  += __shfl_xor(nq, off, 64);
            ncv += __shfl_xor(ncv, off, 64);
        }
        if (lane == 0) {
            float qn = fmaxf(sqrtf(nq), 1e-8f);
            float cn = fmaxf(sqrtf(ncv), 1e-8f);
            gsb[j] = dq / (qn * cn);
        }
    }
    __syncthreads();
    float r = fminf(fmaxf(ratio[0], 0.1f), 0.9f);
    for (int nc = 1 + w; nc < 12; nc += 4) {
        const float* xr = &xs[((long)b * 12 + nc) * 500];
        float s0 = 0.f, s1 = 0.f;
        for (int k = lane; k < 500; k += 64) {
            float x = xr[k];
            s0 += x * clsW[k * 2 + 0];
            s1 += x * clsW[k * 2 + 1];
        }
        #pragma unroll
        for (int off = 1; off < 64; off <<= 1) {
            s0 += __shfl_xor(s0, off, 64);
            s1 += __shfl_xor(s1, off, 64);
        }
        if (lane == 0) {
            s0 += clsb[0]; s1 += clsb[1];
            int jj = nc - 1;
            out[((long)b * 11 + jj) * 2 + 0] = s0;
            out[((long)b * 11 + jj) * 2 + 1] = s1;
            float mx = fmaxf(s0, s1);
            float e0 = expf(s0 - mx), e1 = expf(s1 - mx);
            float p1 = e1 / (e0 + e1);
            out[352 + b * 11 + jj] = gsb[jj] * r + p1 * (1.0f - r);
        }
    }
}

// ---------------------------------------------------------------------------
extern "C" void kernel_launch(void* const* d_in, const int* in_sizes, int n_in,
                              void* d_out, int out_size, void* d_ws, size_t ws_size,
                              hipStream_t stream)
{
    const float* qg       = (const float*)d_in[0];
    const float* cg       = (const float*)d_in[1];
    const float* xr       = (const float*)d_in[2];
    const float* self_W   = (const float*)d_in[3];
    const float* self_b   = (const float*)d_in[4];
    const float* self_g   = (const float*)d_in[5];
    const float* self_be  = (const float*)d_in[6];
    const float* self_al  = (const float*)d_in[7];
    const float* self_la  = (const float*)d_in[8];
    const float* cross_W  = (const float*)d_in[9];
    const float* cross_b  = (const float*)d_in[10];
    const float* cross_g  = (const float*)d_in[11];
    const float* cross_be = (const float*)d_in[12];
    const float* cross_al = (const float*)d_in[13];
    const float* cross_la = (const float*)d_in[14];
    const float* img_W    = (const float*)d_in[15];
    const float* img_b    = (const float*)d_in[16];
    const float* img_g    = (const float*)d_in[17];
    const float* img_be   = (const float*)d_in[18];
    const float* img_al   = (const float*)d_in[19];
    const float* img_la   = (const float*)d_in[20];
    const float* dr_W1    = (const float*)d_in[21];
    const float* dr_b1    = (const float*)d_in[22];
    const float* dr_g1    = (const float*)d_in[23];
    const float* dr_be1   = (const float*)d_in[24];
    const float* dr_W2    = (const float*)d_in[25];
    const float* dr_b2    = (const float*)d_in[26];
    const float* dr_g2    = (const float*)d_in[27];
    const float* dr_be2   = (const float*)d_in[28];
    const float* dr_W3    = (const float*)d_in[29];
    const float* dr_b3    = (const float*)d_in[30];
    const float* dr_g3    = (const float*)d_in[31];
    const float* dr_be3   = (const float*)d_in[32];
    const float* dr_W4    = (const float*)d_in[33];
    const float* dr_b4    = (const float*)d_in[34];
    const float* cls_W    = (const float*)d_in[35];
    const float* cls_b    = (const float*)d_in[36];
    const float* ratio    = (const float*)d_in[37];

    // Workspace layout (floats)
    float* X  = (float*)d_ws;               // 24,576,000
    float* Y  = X  + (long)MROWS * D_;      // 24,576,000
    float* n2 = Y  + (long)MROWS * D_;      // 96,000
    float* xs = n2 + MROWS;                 // 96,000
    float* Y2 = xs + MROWS;                 // 96,000
    size_t need = ((size_t)MROWS * D_ * 2 + (size_t)MROWS * 3) * sizeof(float);
    if (ws_size < need) return;             // insufficient scratch: bail

    // 4 graph layers: self0, cross0, self1, cross1
    for (int layer = 0; layer < 4; ++layer) {
        int li = layer >> 1;
        int crossL = layer & 1;
        const float* Wp = crossL ? cross_W : self_W;
        const float* bp = crossL ? cross_b : self_b;
        const float* gp = crossL ? cross_g : self_g;
        const float* bep = crossL ? cross_be : self_be;
        const float* alp = crossL ? cross_al : self_al;
        const float* lap = crossL ? cross_la : self_la;
        const float* Ain = (layer == 0) ? xr : X;
        gemm_bias_f32<<<dim3(1500, 4), 256, 0, stream>>>(
            Ain, Wp + (long)li * D_ * D_, bp + li * D_, Y, MROWS, D_, D_);
        rowsumsq<<<24000, 256, 0, stream>>>(Y, n2, MROWS);
        graph_attn_f32<<<dim3(32, NG), 256, 0, stream>>>(
            Y, n2, Ain, X, gp + li * D_, bep + li * D_, alp + li, lap + li, crossL);
    }

    // DR MLP -> xs (B, NC, L)
    dr_mlp<<<24000, 256, 0, stream>>>(X, xs,
        dr_W1, dr_b1, dr_g1, dr_be1,
        dr_W2, dr_b2, dr_g2, dr_be2,
        dr_W3, dr_b3, dr_g3, dr_be3,
        dr_W4, dr_b4);

    // 2 img graph layers over NC=12 (feature dim 500)
    for (int li = 0; li < 2; ++li) {
        gemm_bias_f32<<<dim3(3, 8), 256, 0, stream>>>(
            xs, img_W + (long)li * L_ * L_, img_b + li * L_, Y2, NG, L_, L_);
        img_layer<<<NG, 256, 0, stream>>>(
            Y2, xs, img_g + li * L_, img_be + li * L_, img_al + li, img_la + li);
    }

    // Final scoring
    final_k<<<B_, 256, 0, stream>>>(qg, cg, xs, cls_W, cls_b, ratio, (float*)d_out);
}

// Round 2
// 3821.479 us; speedup vs baseline: 3.2481x; 3.2481x over previous
//
#include <hip/hip_runtime.h>
#include <math.h>

// Problem constants
#define B_   16
#define NC_  12
#define L_   500
#define D_   256
#define NG   (B_*NC_)    // 192 graphs
#define MROWS (NG*L_)    // 96000 rows

typedef __attribute__((ext_vector_type(8))) short short8;
typedef __attribute__((ext_vector_type(4))) float f32x4;

__device__ __forceinline__ float gelu_f(float x) {
    return 0.5f * x * (1.0f + erff(x * 0.70710678118654752f));
}

// bf16 helpers (RNE)
__device__ __forceinline__ unsigned short f2bf(float x) {
    union { float f; unsigned u; } v; v.f = x;
    unsigned r = (v.u + 0x7FFFu + ((v.u >> 16) & 1u)) >> 16;
    return (unsigned short)r;
}
__device__ __forceinline__ float bf2f(unsigned short h) {
    union { unsigned u; float f; } v; v.u = ((unsigned)h) << 16;
    return v.f;
}

// ---------------------------------------------------------------------------
// fp32 GEMM writing split-bf16 output: Yh = bf16(C), Yl = bf16(C - Yh)
// 64x64 tile, BK=16, 256 threads, 4x4/thread.
// ---------------------------------------------------------------------------
__global__ __launch_bounds__(256) void gemm_bias_split(
    const float* __restrict__ A, const float* __restrict__ W,
    const float* __restrict__ bias, unsigned short* __restrict__ Yh,
    unsigned short* __restrict__ Yl, int M, int N, int K)
{
    __shared__ __align__(16) float As[64 * 17];
    __shared__ __align__(16) float Bs[16 * 68];
    int t  = threadIdx.x;
    int tx = t & 15, ty = t >> 4;
    int m0 = blockIdx.x * 64;
    int n0 = blockIdx.y * 64;
    float acc[4][4] = {};
    int ktiles = (K + 15) >> 4;
    for (int kt = 0; kt < ktiles; ++kt) {
        int k0 = kt << 4;
        {
            int e = t * 4;
            int r = e >> 4, c = e & 15;
            int row = m0 + r;
            #pragma unroll
            for (int jj = 0; jj < 4; ++jj) {
                int k = k0 + c + jj;
                As[r * 17 + c + jj] = (row < M && k < K) ? A[(long)row * K + k] : 0.0f;
            }
        }
        {
            int e = t * 4;
            int r = e >> 6, c = e & 63;
            int k = k0 + r;
            #pragma unroll
            for (int jj = 0; jj < 4; ++jj) {
                int col = n0 + c + jj;
                Bs[r * 68 + c + jj] = (k < K && col < N) ? W[(long)k * N + col] : 0.0f;
            }
        }
        __syncthreads();
        #pragma unroll
        for (int kk = 0; kk < 16; ++kk) {
            float a0 = As[(ty * 4 + 0) * 17 + kk];
            float a1 = As[(ty * 4 + 1) * 17 + kk];
            float a2 = As[(ty * 4 + 2) * 17 + kk];
            float a3 = As[(ty * 4 + 3) * 17 + kk];
            float4 b = *(const float4*)&Bs[kk * 68 + tx * 4];
            acc[0][0] += a0 * b.x; acc[0][1] += a0 * b.y; acc[0][2] += a0 * b.z; acc[0][3] += a0 * b.w;
            acc[1][0] += a1 * b.x; acc[1][1] += a1 * b.y; acc[1][2] += a1 * b.z; acc[1][3] += a1 * b.w;
            acc[2][0] += a2 * b.x; acc[2][1] += a2 * b.y; acc[2][2] += a2 * b.z; acc[2][3] += a2 * b.w;
            acc[3][0] += a3 * b.x; acc[3][1] += a3 * b.y; acc[3][2] += a3 * b.z; acc[3][3] += a3 * b.w;
        }
        __syncthreads();
    }
    #pragma unroll
    for (int u = 0; u < 4; ++u) {
        int row = m0 + ty * 4 + u;
        if (row >= M) continue;
        ushort4 hv, lv;
        float v0 = acc[u][0] + bias[n0 + tx * 4 + 0];
        float v1 = acc[u][1] + bias[n0 + tx * 4 + 1];
        float v2 = acc[u][2] + bias[n0 + tx * 4 + 2];
        float v3 = acc[u][3] + bias[n0 + tx * 4 + 3];
        hv.x = f2bf(v0); lv.x = f2bf(v0 - bf2f(hv.x));
        hv.y = f2bf(v1); lv.y = f2bf(v1 - bf2f(hv.y));
        hv.z = f2bf(v2); lv.z = f2bf(v2 - bf2f(hv.z));
        hv.w = f2bf(v3); lv.w = f2bf(v3 - bf2f(hv.w));
        long idx = (long)row * N + n0 + tx * 4;
        *(ushort4*)&Yh[idx] = hv;
        *(ushort4*)&Yl[idx] = lv;
    }
}

// ---------------------------------------------------------------------------
// Generic fp32 GEMM (kept for img layers)
// ---------------------------------------------------------------------------
__global__ __launch_bounds__(256) void gemm_bias_f32(
    const float* __restrict__ A, const float* __restrict__ W,
    const float* __restrict__ bias, float* __restrict__ C,
    int M, int N, int K)
{
    __shared__ __align__(16) float As[64 * 17];
    __shared__ __align__(16) float Bs[16 * 68];
    int t  = threadIdx.x;
    int tx = t & 15, ty = t >> 4;
    int m0 = blockIdx.x * 64;
    int n0 = blockIdx.y * 64;
    float acc[4][4] = {};
    int ktiles = (K + 15) >> 4;
    for (int kt = 0; kt < ktiles; ++kt) {
        int k0 = kt << 4;
        {
            int e = t * 4;
            int r = e >> 4, c = e & 15;
            int row = m0 + r;
            #pragma unroll
            for (int jj = 0; jj < 4; ++jj) {
                int k = k0 + c + jj;
                As[r * 17 + c + jj] = (row < M && k < K) ? A[(long)row * K + k] : 0.0f;
            }
        }
        {
            int e = t * 4;
            int r = e >> 6, c = e & 63;
            int k = k0 + r;
            #pragma unroll
            for (int jj = 0; jj < 4; ++jj) {
                int col = n0 + c + jj;
                Bs[r * 68 + c + jj] = (k < K && col < N) ? W[(long)k * N + col] : 0.0f;
            }
        }
        __syncthreads();
        #pragma unroll
        for (int kk = 0; kk < 16; ++kk) {
            float a0 = As[(ty * 4 + 0) * 17 + kk];
            float a1 = As[(ty * 4 + 1) * 17 + kk];
            float a2 = As[(ty * 4 + 2) * 17 + kk];
            float a3 = As[(ty * 4 + 3) * 17 + kk];
            float4 b = *(const float4*)&Bs[kk * 68 + tx * 4];
            acc[0][0] += a0 * b.x; acc[0][1] += a0 * b.y; acc[0][2] += a0 * b.z; acc[0][3] += a0 * b.w;
            acc[1][0] += a1 * b.x; acc[1][1] += a1 * b.y; acc[1][2] += a1 * b.z; acc[1][3] += a1 * b.w;
            acc[2][0] += a2 * b.x; acc[2][1] += a2 * b.y; acc[2][2] += a2 * b.z; acc[2][3] += a2 * b.w;
            acc[3][0] += a3 * b.x; acc[3][1] += a3 * b.y; acc[3][2] += a3 * b.z; acc[3][3] += a3 * b.w;
        }
        __syncthreads();
    }
    #pragma unroll
    for (int u = 0; u < 4; ++u) {
        int row = m0 + ty * 4 + u;
        if (row >= M) continue;
        #pragma unroll
        for (int v = 0; v < 4; ++v) {
            int col = n0 + tx * 4 + v;
            if (col >= N) continue;
            C[(long)row * N + col] = acc[u][v] + bias[col];
        }
    }
}

// ---------------------------------------------------------------------------
// Row sum-of-squares from split-bf16 Y (rows x 256): n2 = sum((Yh+Yl)^2)
// ---------------------------------------------------------------------------
__global__ __launch_bounds__(256) void rowsumsq_split(
    const unsigned short* __restrict__ Yh, const unsigned short* __restrict__ Yl,
    float* __restrict__ n2, int rows)
{
    int t = threadIdx.x;
    int w = t >> 6, lane = t & 63;
    long row = (long)blockIdx.x * 4 + w;
    if (row >= rows) return;
    ushort4 h = *(const ushort4*)&Yh[row * 256 + lane * 4];
    ushort4 l = *(const ushort4*)&Yl[row * 256 + lane * 4];
    float a = bf2f(h.x) + bf2f(l.x);
    float b = bf2f(h.y) + bf2f(l.y);
    float c = bf2f(h.z) + bf2f(l.z);
    float d = bf2f(h.w) + bf2f(l.w);
    float s = a * a + b * b + c * c + d * d;
    s += __shfl_xor(s, 1, 64);  s += __shfl_xor(s, 2, 64);
    s += __shfl_xor(s, 4, 64);  s += __shfl_xor(s, 8, 64);
    s += __shfl_xor(s, 16, 64); s += __shfl_xor(s, 32, 64);
    if (lane == 0) n2[row] = s;
}

// ---------------------------------------------------------------------------
// MFMA flash graph-attention layer (split-bf16, ~fp32 precision).
// Block: 4 waves, each wave owns 16 Q rows (64 rows/block). Grid (8, 192).
// Per 16-col j-tile: S = Qh·Yh^T + Ql·Yh^T + Qh·Yl^T via mfma_16x16x32_bf16,
// online softmax in C-layout, P transposed via wave-private LDS to A-layout,
// O += Ph·Yh + Pl·Yh + Ph·Yl against transposed Y tile. LN+GELU+residual epi.
// LDS strides chosen so all wave accesses are <=2-way bank aliased (free).
// ---------------------------------------------------------------------------
__global__ __launch_bounds__(256, 2) void graph_attn_mfma(
    const unsigned short* __restrict__ Yh, const unsigned short* __restrict__ Yl,
    const float* __restrict__ n2, const float* __restrict__ Xin,
    float* __restrict__ Xout,
    const float* __restrict__ gamma, const float* __restrict__ beta,
    const float* __restrict__ alpha_p, const float* __restrict__ lamda_p,
    int cross)
{
    __shared__ unsigned short Yrh[16][264];   // row-major j-tile (S B-frags)
    __shared__ unsigned short Yrl[16][264];
    __shared__ unsigned short YTh[256][24];   // transposed j-tile (PV B-frags)
    __shared__ unsigned short YTl[256][24];
    __shared__ unsigned short Pbh[4][16][24]; // wave-private P (A-layout src)
    __shared__ unsigned short Pbl[4][16][24];
    __shared__ float q2s[64];
    __shared__ float y2s[16];

    int t    = threadIdx.x;
    int w    = t >> 6;
    int lane = t & 63;
    int mrow = lane & 15;
    int quad = lane >> 4;
    int n    = blockIdx.y;
    int qt   = blockIdx.x;
    int qn   = cross ? (n / NC_) * NC_ : n;
    int q0   = qt * 64;
    float lam = lamda_p[0];

    if (t < 64) {
        int r = q0 + t;
        q2s[t] = (r < L_) ? n2[qn * L_ + r] : 0.0f;
    }
    __syncthreads();

    float q2r[4];
    #pragma unroll
    for (int r = 0; r < 4; ++r) q2r[r] = q2s[w * 16 + quad * 4 + r];

    // Q fragments in registers: rows q0 + w*16 + mrow, k = ks*32 + quad*8 .. +8
    int qrow = q0 + w * 16 + mrow;
    bool qok = qrow < L_;
    const short8* qhp = (const short8*)(Yh + ((long)qn * L_ + qrow) * D_);
    const short8* qlp = (const short8*)(Yl + ((long)qn * L_ + qrow) * D_);
    short8 zf{};
    short8 Qh[8], Ql[8];
    #pragma unroll
    for (int ks = 0; ks < 8; ++ks) {
        Qh[ks] = qok ? qhp[ks * 4 + quad] : zf;
        Ql[ks] = qok ? qlp[ks * 4 + quad] : zf;
    }

    f32x4 O[16];
    #pragma unroll
    for (int i = 0; i < 16; ++i) O[i] = (f32x4){0.f, 0.f, 0.f, 0.f};
    float mrun[4]  = {-3.0e38f, -3.0e38f, -3.0e38f, -3.0e38f};
    float lsum[4]  = {0.f, 0.f, 0.f, 0.f};

    for (int jt = 0; jt < 32; ++jt) {
        int j0 = jt * 16;
        __syncthreads();
        {   // stage Y row-major tile (coalesced global reads)
            int r = t >> 4, c0 = (t & 15) * 16;
            int gj = j0 + r;
            short8 vh0{}, vh1{}, vl0{}, vl1{};
            if (gj < L_) {
                const short8* ph = (const short8*)(Yh + ((long)n * L_ + gj) * D_ + c0);
                const short8* pl = (const short8*)(Yl + ((long)n * L_ + gj) * D_ + c0);
                vh0 = ph[0]; vh1 = ph[1];
                vl0 = pl[0]; vl1 = pl[1];
            }
            *(short8*)&Yrh[r][c0]     = vh0;
            *(short8*)&Yrh[r][c0 + 8] = vh1;
            *(short8*)&Yrl[r][c0]     = vl0;
            *(short8*)&Yrl[r][c0 + 8] = vl1;
            if (t < 16) y2s[t] = (j0 + t < L_) ? n2[n * L_ + j0 + t] : 0.0f;
        }
        __syncthreads();
        {   // LDS transpose: thread t owns dim c=t, writes YT[c][0..15]
            int c = t;
            short8 v0, v1, u0, u1;
            #pragma unroll
            for (int r = 0; r < 8; ++r) {
                v0[r] = (short)Yrh[r][c];     v1[r] = (short)Yrh[r + 8][c];
                u0[r] = (short)Yrl[r][c];     u1[r] = (short)Yrl[r + 8][c];
            }
            *(short8*)&YTh[c][0] = v0;  *(short8*)&YTh[c][8] = v1;
            *(short8*)&YTl[c][0] = u0;  *(short8*)&YTl[c][8] = u1;
        }
        __syncthreads();

        // --- S tile: 16x16, K=256 (8 ksteps) x 3 split products ---
        f32x4 Sa = (f32x4){0.f, 0.f, 0.f, 0.f};
        f32x4 Sb = (f32x4){0.f, 0.f, 0.f, 0.f};
        #pragma unroll
        for (int ks = 0; ks < 8; ++ks) {
            short8 bh = *(const short8*)&Yrh[mrow][ks * 32 + quad * 8];
            short8 bl = *(const short8*)&Yrl[mrow][ks * 32 + quad * 8];
            Sa = __builtin_amdgcn_mfma_f32_16x16x32_bf16(Qh[ks], bh, Sa, 0, 0, 0);
            Sa = __builtin_amdgcn_mfma_f32_16x16x32_bf16(Qh[ks], bl, Sa, 0, 0, 0);
            Sb = __builtin_amdgcn_mfma_f32_16x16x32_bf16(Ql[ks], bh, Sb, 0, 0, 0);
        }
        Sa += Sb;

        // --- logits + online softmax (C-layout: col=lane&15, row=quad*4+r) ---
        int colg = j0 + mrow;
        bool colok = colg < L_;
        float y2v = y2s[mrow];
        float pr[4], fac[4];
        #pragma unroll
        for (int r = 0; r < 4; ++r) {
            int rowg = q0 + w * 16 + quad * 4 + r;
            float d2 = q2r[r] + y2v - 2.0f * Sa[r];
            float lg = colok ? (-2.0f * sqrtf(fmaxf(d2, 0.0f)) + ((rowg == colg) ? lam : 0.0f))
                             : -1.0e30f;
            float tm = lg;
            tm = fmaxf(tm, __shfl_xor(tm, 1, 16));
            tm = fmaxf(tm, __shfl_xor(tm, 2, 16));
            tm = fmaxf(tm, __shfl_xor(tm, 4, 16));
            tm = fmaxf(tm, __shfl_xor(tm, 8, 16));
            float mn = fmaxf(mrun[r], tm);
            fac[r] = expf(mrun[r] - mn);
            pr[r]  = expf(lg - mn);
            float ps = pr[r];
            ps += __shfl_xor(ps, 1, 16); ps += __shfl_xor(ps, 2, 16);
            ps += __shfl_xor(ps, 4, 16); ps += __shfl_xor(ps, 8, 16);
            lsum[r] = lsum[r] * fac[r] + ps;
            mrun[r] = mn;
        }
        f32x4 facv = (f32x4){fac[0], fac[1], fac[2], fac[3]};
        #pragma unroll
        for (int i = 0; i < 16; ++i) O[i] *= facv;

        // --- P to LDS (split), wave-private; same-wave RAW needs no barrier ---
        #pragma unroll
        for (int r = 0; r < 4; ++r) {
            unsigned short ph = f2bf(pr[r]);
            unsigned short pl = f2bf(pr[r] - bf2f(ph));
            Pbh[w][quad * 4 + r][mrow] = ph;
            Pbl[w][quad * 4 + r][mrow] = pl;
        }
        short8 Pha = zf, Pla = zf;
        if (quad < 2) {
            Pha = *(const short8*)&Pbh[w][mrow][quad * 8];
            Pla = *(const short8*)&Pbl[w][mrow][quad * 8];
        }

        // --- PV: O[nt] += P * Ytile (K=16 real, upper half zeroed) ---
        #pragma unroll
        for (int nt = 0; nt < 16; ++nt) {
            short8 bh = zf, bl = zf;
            if (quad < 2) {
                bh = *(const short8*)&YTh[nt * 16 + mrow][quad * 8];
                bl = *(const short8*)&YTl[nt * 16 + mrow][quad * 8];
            }
            O[nt] = __builtin_amdgcn_mfma_f32_16x16x32_bf16(Pha, bh, O[nt], 0, 0, 0);
            O[nt] = __builtin_amdgcn_mfma_f32_16x16x32_bf16(Pla, bh, O[nt], 0, 0, 0);
            O[nt] = __builtin_amdgcn_mfma_f32_16x16x32_bf16(Pha, bl, O[nt], 0, 0, 0);
        }
    }

    // --- normalize + LN + GELU + residual epilogue ---
    float inv[4], mean[4], rsv[4];
    #pragma unroll
    for (int r = 0; r < 4; ++r) inv[r] = 1.0f / lsum[r];
    float s[4] = {0.f, 0.f, 0.f, 0.f};
    #pragma unroll
    for (int i = 0; i < 16; ++i) {
        #pragma unroll
        for (int r = 0; r < 4; ++r) { O[i][r] *= inv[r]; s[r] += O[i][r]; }
    }
    #pragma unroll
    for (int r = 0; r < 4; ++r) {
        float v = s[r];
        v += __shfl_xor(v, 1, 16); v += __shfl_xor(v, 2, 16);
        v += __shfl_xor(v, 4, 16); v += __shfl_xor(v, 8, 16);
        mean[r] = v * (1.0f / 256.0f);
    }
    float vv[4] = {0.f, 0.f, 0.f, 0.f};
    #pragma unroll
    for (int i = 0; i < 16; ++i) {
        #pragma unroll
        for (int r = 0; r < 4; ++r) { float d = O[i][r] - mean[r]; vv[r] += d * d; }
    }
    #pragma unroll
    for (int r = 0; r < 4; ++r) {
        float v = vv[r];
        v += __shfl_xor(v, 1, 16); v += __shfl_xor(v, 2, 16);
        v += __shfl_xor(v, 4, 16); v += __shfl_xor(v, 8, 16);
        rsv[r] = rsqrtf(v * (1.0f / 256.0f) + 1e-6f);
    }
    float a = fminf(fmaxf(alpha_p[0], 0.1f), 0.9f);
    #pragma unroll
    for (int nt = 0; nt < 16; ++nt) {
        int col = nt * 16 + mrow;
        float g  = gamma[col];
        float be = beta[col];
        #pragma unroll
        for (int r = 0; r < 4; ++r) {
            int rowg = q0 + w * 16 + quad * 4 + r;
            if (rowg < L_) {
                long idx = ((long)n * L_ + rowg) * D_ + col;
                float xin = Xin[idx];
                float hn = g * (O[nt][r] - mean[r]) * rsv[r] + be;
                Xout[idx] = (1.0f - a) * xin + a * gelu_f(hn);
            }
        }
    }
}

// ---------------------------------------------------------------------------
// Fused dimension-reduction MLP: 256->64->32->16->1, LN+GELU between.
// ---------------------------------------------------------------------------
__global__ __launch_bounds__(256) void dr_mlp(
    const float* __restrict__ X, float* __restrict__ xs,
    const float* __restrict__ W1, const float* __restrict__ b1,
    const float* __restrict__ g1, const float* __restrict__ be1,
    const float* __restrict__ W2, const float* __restrict__ b2,
    const float* __restrict__ g2, const float* __restrict__ be2,
    const float* __restrict__ W3, const float* __restrict__ b3,
    const float* __restrict__ g3, const float* __restrict__ be3,
    const float* __restrict__ W4, const float* __restrict__ b4)
{
    __shared__ __align__(16) float xrow[4][256];
    __shared__ float s1[4][64];
    __shared__ float s2[4][32];
    __shared__ float s3[4][16];
    int t = threadIdx.x;
    int w = t >> 6, lane = t & 63;
    long row = (long)blockIdx.x * 4 + w;

    *(float4*)&xrow[w][lane * 4] = *(const float4*)&X[row * 256 + lane * 4];

    int o = lane;
    float a0 = 0.f, a1 = 0.f, a2 = 0.f, a3 = 0.f;
    #pragma unroll 8
    for (int k4 = 0; k4 < 64; ++k4) {
        float4 xv = *(const float4*)&xrow[w][k4 * 4];
        a0 += xv.x * W1[(k4 * 4 + 0) * 64 + o];
        a1 += xv.y * W1[(k4 * 4 + 1) * 64 + o];
        a2 += xv.z * W1[(k4 * 4 + 2) * 64 + o];
        a3 += xv.w * W1[(k4 * 4 + 3) * 64 + o];
    }
    float acc = b1[o] + ((a0 + a1) + (a2 + a3));
    float sum = acc;
    #pragma unroll
    for (int off = 1; off < 64; off <<= 1) sum += __shfl_xor(sum, off, 64);
    float mean = sum * (1.0f / 64.0f);
    float dlt = acc - mean;
    float v2 = dlt * dlt;
    #pragma unroll
    for (int off = 1; off < 64; off <<= 1) v2 += __shfl_xor(v2, off, 64);
    float rs = rsqrtf(v2 * (1.0f / 64.0f) + 1e-6f);
    s1[w][o] = gelu_f(g1[o] * dlt * rs + be1[o]);

    int o2 = lane & 31;
    float acc2 = b2[o2];
    #pragma unroll
    for (int k = 0; k < 64; ++k) acc2 += s1[w][k] * W2[k * 32 + o2];
    float sum2 = acc2;
    #pragma unroll
    for (int off = 1; off < 32; off <<= 1) sum2 += __shfl_xor(sum2, off, 32);
    float mean2 = sum2 * (1.0f / 32.0f);
    float d2 = acc2 - mean2;
    float v22 = d2 * d2;
    #pragma unroll
    for (int off = 1; off < 32; off <<= 1) v22 += __shfl_xor(v22, off, 32);
    float rs2 = rsqrtf(v22 * (1.0f / 32.0f) + 1e-6f);
    s2[w][o2] = gelu_f(g2[o2] * d2 * rs2 + be2[o2]);

    int o3 = lane & 15;
    float acc3 = b3[o3];
    #pragma unroll
    for (int k = 0; k < 32; ++k) acc3 += s2[w][k] * W3[k * 16 + o3];
    float sum3 = acc3;
    #pragma unroll
    for (int off = 1; off < 16; off <<= 1) sum3 += __shfl_xor(sum3, off, 16);
    float mean3 = sum3 * (1.0f / 16.0f);
    float d3 = acc3 - mean3;
    float v23 = d3 * d3;
    #pragma unroll
    for (int off = 1; off < 16; off <<= 1) v23 += __shfl_xor(v23, off, 16);
    float rs3 = rsqrtf(v23 * (1.0f / 16.0f) + 1e-6f);
    s3[w][o3] = gelu_f(g3[o3] * d3 * rs3 + be3[o3]);

    float acc4 = b4[0];
    #pragma unroll
    for (int k = 0; k < 16; ++k) acc4 += s3[w][k] * W4[k];
    if (lane == 0) xs[row] = gelu_f(acc4);
}

// ---------------------------------------------------------------------------
// Img graph layer over NC=12 nodes, feature dim L=500. One block per (b, i).
// ---------------------------------------------------------------------------
__global__ __launch_bounds__(256) void img_layer(
    const float* __restrict__ Y2, float* __restrict__ xs,
    const float* __restrict__ gamma, const float* __restrict__ beta,
    const float* __restrict__ alpha_p, const float* __restrict__ lamda_p)
{
    __shared__ float ys[12][500];
    __shared__ float hs[500];
    __shared__ float wred[4][24];
    __shared__ float ps[12];
    __shared__ float stats[2];
    int t = threadIdx.x;
    int w = t >> 6, lane = t & 63;
    int b = blockIdx.x / 12;
    int i = blockIdx.x - b * 12;

    for (int idx = t; idx < 6000; idx += 256)
        ys[idx / 500][idx % 500] = Y2[(long)b * 6000 + idx];
    __syncthreads();

    float dloc[12], nloc[12];
    #pragma unroll
    for (int j = 0; j < 12; ++j) { dloc[j] = 0.f; nloc[j] = 0.f; }
    for (int k = t; k < 500; k += 256) {
        float yi = ys[i][k];
        #pragma unroll
        for (int j = 0; j < 12; ++j) {
            float yj = ys[j][k];
            dloc[j] += yi * yj;
            nloc[j] += yj * yj;
        }
    }
    #pragma unroll
    for (int q = 0; q < 24; ++q) {
        float v = (q < 12) ? dloc[q] : nloc[q - 12];
        v += __shfl_xor(v, 1, 64);  v += __shfl_xor(v, 2, 64);
        v += __shfl_xor(v, 4, 64);  v += __shfl_xor(v, 8, 64);
        v += __shfl_xor(v, 16, 64); v += __shfl_xor(v, 32, 64);
        if (lane == 0) wred[w][q] = v;
    }
    __syncthreads();
    if (t == 0) {
        float lam = lamda_p[0];
        float dot[12], nn[12];
        #pragma unroll
        for (int q = 0; q < 12; ++q) {
            dot[q] = wred[0][q] + wred[1][q] + wred[2][q] + wred[3][q];
            nn[q]  = wred[0][12+q] + wred[1][12+q] + wred[2][12+q] + wred[3][12+q];
        }
        float ni = nn[i];
        float lg[12];
        float mx = -3.0e38f;
        #pragma unroll
        for (int j = 0; j < 12; ++j) {
            float dd2 = fmaxf(ni + nn[j] - 2.0f * dot[j], 0.0f);
            lg[j] = -2.0f * sqrtf(dd2) + ((j == i) ? lam : 0.0f);
            mx = fmaxf(mx, lg[j]);
        }
        float se = 0.f;
        #pragma unroll
        for (int j = 0; j < 12; ++j) { lg[j] = expf(lg[j] - mx); se += lg[j]; }
        float inv = 1.0f / se;
        #pragma unroll
        for (int j = 0; j < 12; ++j) ps[j] = lg[j] * inv;
    }
    __syncthreads();
    float pl[12];
    #pragma unroll
    for (int j = 0; j < 12; ++j) pl[j] = ps[j];
    float lsum = 0.f;
    for (int k = t; k < 500; k += 256) {
        float h = 0.f;
        #pragma unroll
        for (int j = 0; j < 12; ++j) h += pl[j] * ys[j][k];
        hs[k] = h;
        lsum += h;
    }
    {
        float v = lsum;
        v += __shfl_xor(v, 1, 64);  v += __shfl_xor(v, 2, 64);
        v += __shfl_xor(v, 4, 64);  v += __shfl_xor(v, 8, 64);
        v += __shfl_xor(v, 16, 64); v += __shfl_xor(v, 32, 64);
        if (lane == 0) wred[w][0] = v;
    }
    __syncthreads();
    if (t == 0) stats[0] = (wred[0][0] + wred[1][0] + wred[2][0] + wred[3][0]) * (1.0f / 500.0f);
    __syncthreads();
    float mean = stats[0];
    float vloc = 0.f;
    for (int k = t; k < 500; k += 256) { float d = hs[k] - mean; vloc += d * d; }
    {
        float v = vloc;
        v += __shfl_xor(v, 1, 64);  v += __shfl_xor(v, 2, 64);
        v += __shfl_xor(v, 4, 64);  v += __shfl_xor(v, 8, 64);
        v += __shfl_xor(v, 16, 64); v += __shfl_xor(v, 32, 64);
        if (lane == 0) wred[w][1] = v;
    }
    __syncthreads();
    if (t == 0) stats[1] = rsqrtf((wred[0][1] + wred[1][1] + wred[2][1] + wred[3][1]) * (1.0f / 500.0f) + 1e-6f);
    __syncthreads();
    float rsv = stats[1];
    float a = fminf(fmaxf(alpha_p[0], 0.1f), 0.9f);
    for (int k = t; k < 500; k += 256) {
        float hn = gamma[k] * (hs[k] - mean) * rsv + beta[k];
        float gl = gelu_f(hn);
        long idx = ((long)b * 12 + i) * 500 + k;
        xs[idx] = (1.0f - a) * xs[idx] + a * gl;
    }
}

// ---------------------------------------------------------------------------
// Final scoring
// ---------------------------------------------------------------------------
__global__ __launch_bounds__(256) void final_k(
    const float* __restrict__ qg, const float* __restrict__ cg,
    const float* __restrict__ xs, const float* __restrict__ clsW,
    const float* __restrict__ clsb, const float* __restrict__ ratio,
    float* __restrict__ out)
{
    __shared__ float gsb[11];
    int b = blockIdx.x;
    int t = threadIdx.x;
    int w = t >> 6, lane = t & 63;

    for (int j = w; j < 11; j += 4) {
        const float* q = &qg[b * 256];
        const float* c = &cg[((long)b * 11 + j) * 256];
        float4 qv = *(const float4*)&q[lane * 4];
        float4 cv = *(const float4*)&c[lane * 4];
        float dq  = qv.x * cv.x + qv.y * cv.y + qv.z * cv.z + qv.w * cv.w;
        float nq  = qv.x * qv.x + qv.y * qv.y + qv.z * qv.z + qv.w * qv.w;
        float ncv = cv.x * cv.x + cv.y * cv.y + cv.z * cv.z + cv.w * cv.w;
        #pragma unroll
        for (int off = 1; off < 64; off <<= 1) {
            dq  += __shfl_xor(dq, off, 64);
            nq  += __shfl_xor(nq, off, 64);
            ncv += __shfl_xor(ncv, off, 64);
        }
        if (lane == 0) {
            float qn = fmaxf(sqrtf(nq), 1e-8f);
            float cn = fmaxf(sqrtf(ncv), 1e-8f);
            gsb[j] = dq / (qn * cn);
        }
    }
    __syncthreads();
    float r = fminf(fmaxf(ratio[0], 0.1f), 0.9f);
    for (int nc = 1 + w; nc < 12; nc += 4) {
        const float* xr = &xs[((long)b * 12 + nc) * 500];
        float s0 = 0.f, s1 = 0.f;
        for (int k = lane; k < 500; k += 64) {
            float x = xr[k];
            s0 += x * clsW[k * 2 + 0];
            s1 += x * clsW[k * 2 + 1];
        }
        #pragma unroll
        for (int off = 1; off < 64; off <<= 1) {
            s0 += __shfl_xor(s0, off, 64);
            s1 += __shfl_xor(s1, off, 64);
        }
        if (lane == 0) {
            s0 += clsb[0]; s1 += clsb[1];
            int jj = nc - 1;
            out[((long)b * 11 + jj) * 2 + 0] = s0;
            out[((long)b * 11 + jj) * 2 + 1] = s1;
            float mx = fmaxf(s0, s1);
            float e0 = expf(s0 - mx), e1 = expf(s1 - mx);
            float p1 = e1 / (e0 + e1);
            out[352 + b * 11 + jj] = gsb[jj] * r + p1 * (1.0f - r);
        }
    }
}

// ---------------------------------------------------------------------------
extern "C" void kernel_launch(void* const* d_in, const int* in_sizes, int n_in,
                              void* d_out, int out_size, void* d_ws, size_t ws_size,
                              hipStream_t stream)
{
    const float* qg       = (const float*)d_in[0];
    const float* cg       = (const float*)d_in[1];
    const float* xr       = (const float*)d_in[2];
    const float* self_W   = (const float*)d_in[3];
    const float* self_b   = (const float*)d_in[4];
    const float* self_g   = (const float*)d_in[5];
    const float* self_be  = (const float*)d_in[6];
    const float* self_al  = (const float*)d_in[7];
    const float* self_la  = (const float*)d_in[8];
    const float* cross_W  = (const float*)d_in[9];
    const float* cross_b  = (const float*)d_in[10];
    const float* cross_g  = (const float*)d_in[11];
    const float* cross_be = (const float*)d_in[12];
    const float* cross_al = (const float*)d_in[13];
    const float* cross_la = (const float*)d_in[14];
    const float* img_W    = (const float*)d_in[15];
    const float* img_b    = (const float*)d_in[16];
    const float* img_g    = (const float*)d_in[17];
    const float* img_be   = (const float*)d_in[18];
    const float* img_al   = (const float*)d_in[19];
    const float* img_la   = (const float*)d_in[20];
    const float* dr_W1    = (const float*)d_in[21];
    const float* dr_b1    = (const float*)d_in[22];
    const float* dr_g1    = (const float*)d_in[23];
    const float* dr_be1   = (const float*)d_in[24];
    const float* dr_W2    = (const float*)d_in[25];
    const float* dr_b2    = (const float*)d_in[26];
    const float* dr_g2    = (const float*)d_in[27];
    const float* dr_be2   = (const float*)d_in[28];
    const float* dr_W3    = (const float*)d_in[29];
    const float* dr_b3    = (const float*)d_in[30];
    const float* dr_g3    = (const float*)d_in[31];
    const float* dr_be3   = (const float*)d_in[32];
    const float* dr_W4    = (const float*)d_in[33];
    const float* dr_b4    = (const float*)d_in[34];
    const float* cls_W    = (const float*)d_in[35];
    const float* cls_b    = (const float*)d_in[36];
    const float* ratio    = (const float*)d_in[37];

    // Workspace layout
    float* X = (float*)d_ws;                                   // MROWS*D fp32
    unsigned short* Yh = (unsigned short*)(X + (long)MROWS * D_);
    unsigned short* Yl = Yh + (long)MROWS * D_;
    float* n2p = (float*)(Yl + (long)MROWS * D_);
    float* xs  = n2p + MROWS;
    float* Y2  = xs + MROWS;
    size_t need = (size_t)MROWS * D_ * 4 + (size_t)MROWS * D_ * 2 * 2 + (size_t)MROWS * 3 * 4;
    if (ws_size < need) return;

    // 4 graph layers: self0, cross0, self1, cross1
    for (int layer = 0; layer < 4; ++layer) {
        int li = layer >> 1;
        int crossL = layer & 1;
        const float* Wp  = crossL ? cross_W  : self_W;
        const float* bp  = crossL ? cross_b  : self_b;
        const float* gp  = crossL ? cross_g  : self_g;
        const float* bep = crossL ? cross_be : self_be;
        const float* alp = crossL ? cross_al : self_al;
        const float* lap = crossL ? cross_la : self_la;
        const float* Ain = (layer == 0) ? xr : X;
        gemm_bias_split<<<dim3(1500, 4), 256, 0, stream>>>(
            Ain, Wp + (long)li * D_ * D_, bp + li * D_, Yh, Yl, MROWS, D_, D_);
        rowsumsq_split<<<24000, 256, 0, stream>>>(Yh, Yl, n2p, MROWS);
        graph_attn_mfma<<<dim3(8, NG), 256, 0, stream>>>(
            Yh, Yl, n2p, Ain, X, gp + li * D_, bep + li * D_, alp + li, lap + li, crossL);
    }

    // DR MLP -> xs (B, NC, L)
    dr_mlp<<<24000, 256, 0, stream>>>(X, xs,
        dr_W1, dr_b1, dr_g1, dr_be1,
        dr_W2, dr_b2, dr_g2, dr_be2,
        dr_W3, dr_b3, dr_g3, dr_be3,
        dr_W4, dr_b4);

    // 2 img graph layers over NC=12
    for (int li = 0; li < 2; ++li) {
        gemm_bias_f32<<<dim3(3, 8), 256, 0, stream>>>(
            xs, img_W + (long)li * L_ * L_, img_b + li * L_, Y2, NG, L_, L_);
        img_layer<<<NG, 256, 0, stream>>>(
            Y2, xs, img_g + li * L_, img_be + li * L_, img_al + li, img_la + li);
    }

    // Final scoring
    final_k<<<B_, 256, 0, stream>>>(qg, cg, xs, cls_W, cls_b, ratio, (float*)d_out);
}